// Round 22
// baseline (118.313 us; speedup 1.0000x reference)
//
#include <hip/hip_runtime.h>
#include <hip/hip_bf16.h>

#define BATCH 16
#define SEQ   2048
#define HD    128
#define QBLK  64
#define KVBLK 32
#define NT    (SEQ / KVBLK)

typedef __attribute__((ext_vector_type(8))) short bf16x8;
typedef __attribute__((ext_vector_type(4))) float f32x4;
typedef __attribute__((ext_vector_type(4))) short s16x4;

__device__ __forceinline__ short f2bf(float x) {
    __hip_bfloat16 h = __float2bfloat16(x);
    return *reinterpret_cast<short*>(&h);
}

// r18 base (111.3us) + swapped-QK^T register-resident P (T12-adapted):
// mfma(kf,qf) computes S^T with q LANE-LOCAL (q=lc, kv=lg*4+r+16nt) -- A/B
// frags share the same lane map, so the swap is free. P then never touches
// LDS: pack pairs to 4 dwords, redistribute with 4 ds_bpermute (__shfl) to
// the PV A-frag layout. Removes the 8x ds_write + lgkm + ds_read_b128 serial
// roundtrip between QK and PV. ISF loads become 2 transposed float4s.
__global__ __launch_bounds__(256, 2)
void attn_fused(const float* __restrict__ Q, const float* __restrict__ K,
                const float* __restrict__ V, const float* __restrict__ ISF,
                float* __restrict__ O)
{
    const int tid  = threadIdx.x;
    const int lane = tid & 63;
    const int wv   = tid >> 6;      // wave 0..3, owns q-rows [wv*16, wv*16+16)
    const int lg   = lane >> 4;     // 16-lane group 0..3
    const int lc   = lane & 15;

    const int bidx = blockIdx.x;
    const int b    = bidx >> 5;            // 32 q-tiles per batch
    const int q0   = (bidx & 31) * QBLK;

    __shared__ short Klds[2][32 * 128];    // XOR-swizzled 16B chunks
    __shared__ short Vtlds[2][128 * 40];   // transposed V [d][kv], stride 40 shorts

    // ---- hoist Q fragments: lane holds Q[q0+wv*16+lc][ks*32+lg*8+j] ----
    bf16x8 qf[4];
    {
        const float* qrow = Q + ((size_t)b * SEQ + q0 + wv * 16 + lc) * HD;
        #pragma unroll
        for (int ks = 0; ks < 4; ++ks) {
            const float* p = qrow + ks * 32 + lg * 8;
            float4 x0 = *reinterpret_cast<const float4*>(p);
            float4 x1 = *reinterpret_cast<const float4*>(p + 4);
            bf16x8 f;
            f[0]=f2bf(x0.x); f[1]=f2bf(x0.y); f[2]=f2bf(x0.z); f[3]=f2bf(x0.w);
            f[4]=f2bf(x1.x); f[5]=f2bf(x1.y); f[6]=f2bf(x1.z); f[7]=f2bf(x1.w);
            qf[ks] = f;
        }
    }

    f32x4 oacc[8];
    #pragma unroll
    for (int i = 0; i < 8; ++i) oacc[i] = (f32x4){0.f, 0.f, 0.f, 0.f};
    float l_part = 0.f;             // partial row sum for q = lc (lane-local)

    const float* kbase = K + (size_t)b * SEQ * HD;
    const float* vbase = V + (size_t)b * SEQ * HD;
    // ISF row for THIS lane's q = lc (swapped layout)
    const float* ibase = ISF + ((size_t)b * SEQ + q0 + wv * 16 + lc) * SEQ;

    float4 kreg[4];
    float  vreg[4][4];
    float4 isf_nxt[2];
    float  isf_cur[8];              // rcp(isf)*log2e at (q=lc, kv=nt*16+lg*4+r)

    auto LOAD = [&](int kv0) {
        const float* kb = kbase + (size_t)kv0 * HD;
        const float* vb = vbase + (size_t)kv0 * HD;
        #pragma unroll
        for (int r = 0; r < 4; ++r) {
            int idx = r * 256 + tid;
            kreg[r] = *reinterpret_cast<const float4*>(kb + (size_t)(idx >> 5) * HD + (idx & 31) * 4);
        }
        #pragma unroll
        for (int r = 0; r < 4; ++r) {
            int idx = r * 256 + tid;
            int d = idx & 127, kq = idx >> 7;
            #pragma unroll
            for (int j = 0; j < 4; ++j)
                vreg[r][j] = vb[(size_t)(kq * 4 + j) * HD + d];
        }
    };
    auto LOAD_ISF = [&](int kv0) {
        #pragma unroll
        for (int nt = 0; nt < 2; ++nt)
            isf_nxt[nt] = *reinterpret_cast<const float4*>(ibase + kv0 + nt * 16 + lg * 4);
    };
    auto STORE = [&](int buf) {
        #pragma unroll
        for (int r = 0; r < 4; ++r) {
            int idx = r * 256 + tid;
            int kvr = idx >> 5, d4 = idx & 31;
            s16x4 s;
            s[0]=f2bf(kreg[r].x); s[1]=f2bf(kreg[r].y); s[2]=f2bf(kreg[r].z); s[3]=f2bf(kreg[r].w);
            int chunk = (d4 >> 1) ^ (kvr & 7);
            *reinterpret_cast<s16x4*>(&Klds[buf][kvr * 128 + chunk * 8 + (d4 & 1) * 4]) = s;
        }
        #pragma unroll
        for (int r = 0; r < 4; ++r) {
            int idx = r * 256 + tid;
            int d = idx & 127, kq = idx >> 7;
            s16x4 s;
            #pragma unroll
            for (int j = 0; j < 4; ++j) s[j] = f2bf(vreg[r][j]);
            *reinterpret_cast<s16x4*>(&Vtlds[buf][d * 40 + kq * 4]) = s;
        }
    };

    // ---- prologue: tile 0 into buf 0 ----
    LOAD(0);
    LOAD_ISF(0);
    STORE(0);
    __syncthreads();
    #pragma unroll
    for (int nt = 0; nt < 2; ++nt)
        #pragma unroll
        for (int r = 0; r < 4; ++r)
            isf_cur[nt * 4 + r] = __builtin_amdgcn_rcpf(isf_nxt[nt][r]) * 1.44269504f;

    // bpermute source lanes (constant per thread)
    const int srcA = lc + 16 * (2 * (lg & 1) + (lg >> 1));
    const int srcB = lc + 16 * (2 * (lg & 1) + 1 - (lg >> 1));
    const bool hi  = (lg >> 1) != 0;

    int cur = 0;
    for (int t = 0; t < NT; ++t) {
        const int kv0n = (t + 1) * KVBLK;
        const bool more = (t + 1 < NT);
        if (more) { LOAD(kv0n); LOAD_ISF(kv0n); }   // in flight under compute

        // ---- S^T = K·Q^T (swapped): lane holds S[q=lc][kv=nt*16+lg*4+r] ----
        f32x4 sacc[2], sacc2[2];
        #pragma unroll
        for (int nt = 0; nt < 2; ++nt) {
            sacc[nt]  = (f32x4){0.f,0.f,0.f,0.f};
            sacc2[nt] = (f32x4){0.f,0.f,0.f,0.f};
        }
        __builtin_amdgcn_s_setprio(1);
        #pragma unroll
        for (int nt = 0; nt < 2; ++nt) {
            int n = lc + nt * 16;
            #pragma unroll
            for (int ks = 0; ks < 4; ++ks) {
                int chunk = (ks * 4 + lg) ^ (n & 7);
                bf16x8 bf = *reinterpret_cast<const bf16x8*>(&Klds[cur][n * 128 + chunk * 8]);
                if (ks < 2) sacc[nt]  = __builtin_amdgcn_mfma_f32_16x16x32_bf16(bf, qf[ks], sacc[nt],  0, 0, 0);
                else        sacc2[nt] = __builtin_amdgcn_mfma_f32_16x16x32_bf16(bf, qf[ks], sacc2[nt], 0, 0, 0);
            }
        }
        __builtin_amdgcn_s_setprio(0);

        // ---- P = exp2(S * rcp(isf)*log2e), lane-local in q ----
        float p[2][4];
        #pragma unroll
        for (int nt = 0; nt < 2; ++nt) {
            f32x4 s4 = sacc[nt] + sacc2[nt];
            #pragma unroll
            for (int r = 0; r < 4; ++r)
                p[nt][r] = __builtin_amdgcn_exp2f(s4[r] * isf_cur[nt * 4 + r]);
        }
        l_part += ((p[0][0] + p[0][1]) + (p[0][2] + p[0][3]))
                + ((p[1][0] + p[1][1]) + (p[1][2] + p[1][3]));

        // ---- pack bf16 pairs: pk[nt][s] = (P[kv+1]<<16)|P[kv], kv=nt*16+lg*4+2s ----
        unsigned pk[2][2];
        #pragma unroll
        for (int nt = 0; nt < 2; ++nt)
            #pragma unroll
            for (int s = 0; s < 2; ++s)
                pk[nt][s] = (unsigned)(unsigned short)f2bf(p[nt][2 * s])
                          | ((unsigned)(unsigned short)f2bf(p[nt][2 * s + 1]) << 16);

        // ---- redistribute to PV A-frag via 4 bpermutes (map verified) ----
        unsigned vA0 = (lg & 1) ? pk[1][0] : pk[0][0];
        unsigned vA1 = (lg & 1) ? pk[1][1] : pk[0][1];
        unsigned vB0 = (lg & 1) ? pk[0][0] : pk[1][0];
        unsigned vB1 = (lg & 1) ? pk[0][1] : pk[1][1];
        unsigned rA0 = (unsigned)__shfl((int)vA0, srcA);
        unsigned rA1 = (unsigned)__shfl((int)vA1, srcA);
        unsigned rB0 = (unsigned)__shfl((int)vB0, srcB);
        unsigned rB1 = (unsigned)__shfl((int)vB1, srcB);
        union { unsigned u[4]; bf16x8 v; } pau;
        pau.u[0] = hi ? rB0 : rA0;
        pau.u[1] = hi ? rB1 : rA1;
        pau.u[2] = hi ? rA0 : rB0;
        pau.u[3] = hi ? rA1 : rB1;
        bf16x8 pa = pau.v;

        // ---- O += P·V ----
        __builtin_amdgcn_s_setprio(1);
        #pragma unroll
        for (int dt = 0; dt < 8; ++dt) {
            bf16x8 vf = *reinterpret_cast<const bf16x8*>(&Vtlds[cur][(lc + dt * 16) * 40 + lg * 8]);
            oacc[dt] = __builtin_amdgcn_mfma_f32_16x16x32_bf16(pa, vf, oacc[dt], 0, 0, 0);
        }
        __builtin_amdgcn_s_setprio(0);

        // ---- land tile t+1 in the other buffer; single barrier per iter ----
        if (more) STORE(cur ^ 1);
        __syncthreads();
        cur ^= 1;
        #pragma unroll
        for (int nt = 0; nt < 2; ++nt)
            #pragma unroll
            for (int r = 0; r < 4; ++r)
                isf_cur[nt * 4 + r] = __builtin_amdgcn_rcpf(isf_nxt[nt][r]) * 1.44269504f;
    }

    // ---- epilogue: finish row sums (lanes with same lc share q) ----
    l_part += __shfl_xor(l_part, 16, 64);
    l_part += __shfl_xor(l_part, 32, 64);

    float* ob = O + ((size_t)b * SEQ + q0 + wv * 16) * HD;
    #pragma unroll
    for (int r = 0; r < 4; ++r) {
        float inv_l = 1.0f / __shfl(l_part, lg * 4 + r, 64);  // l for q-row lg*4+r
        float* orow = ob + (size_t)(lg * 4 + r) * HD;
        #pragma unroll
        for (int dt = 0; dt < 8; ++dt)
            orow[lc + dt * 16] = oacc[dt][r] * inv_l;
    }
}

extern "C" void kernel_launch(void* const* d_in, const int* in_sizes, int n_in,
                              void* d_out, int out_size, void* d_ws, size_t ws_size,
                              hipStream_t stream) {
    const float* q   = (const float*)d_in[0];
    const float* k   = (const float*)d_in[1];
    const float* v   = (const float*)d_in[2];
    const float* isf = (const float*)d_in[3];
    float* out = (float*)d_out;
    dim3 grid(BATCH * (SEQ / QBLK));   // 512 blocks
    attn_fused<<<grid, 256, 0, stream>>>(q, k, v, isf, out);
}